// Round 5
// baseline (426.023 us; speedup 1.0000x reference)
//
#include <hip/hip_runtime.h>
#include <stdint.h>

typedef __attribute__((ext_vector_type(8))) short short8;
typedef __attribute__((ext_vector_type(4))) float floatx4;
typedef unsigned short ushort_t;

#define E_TOTAL 640000
#define N_NODES 20000
#define M_BLK   128
#define N_TILES (E_TOTAL / M_BLK)   // 5000
#define XS2_LD  132   // 128 + 4 fp16 pad -> row stride 264B (2-bank row step)
#define HS_LD   136   // 128 + 8 fp16 pad -> row stride 272B
#define XS_LD   264   // fallback kernel only

__device__ __forceinline__ unsigned short f2h(float f){
    _Float16 h = (_Float16)f;                  // v_cvt_f16_f32, RNE
    union { _Float16 h; unsigned short u; } v; v.h = h; return v.u;
}
__device__ __forceinline__ unsigned pk2h(float a, float b){
    return (unsigned)f2h(a) | ((unsigned)f2h(b) << 16);
}

// Repack W1[256,128] / W2[128,64] (row-major fp32) into fp16 MFMA B-fragment
// order: lane's 8 B-elements contiguous (one 16B load).
__global__ void repack_w(const float* __restrict__ W1,
                         const float* __restrict__ W2,
                         ushort_t* __restrict__ W1p,
                         ushort_t* __restrict__ W2p){
    int tid = blockIdx.x * 256 + threadIdx.x;
    if (tid < 8*8*64){
        int kt = tid >> 9, nt = (tid >> 6) & 7, l = tid & 63;
        int q = l >> 4, c = l & 15;
        ushort_t tmp[8];
        #pragma unroll
        for (int j = 0; j < 8; j++)
            tmp[j] = f2h(W1[(kt*32 + q*8 + j)*128 + nt*16 + c]);
        #pragma unroll
        for (int j = 0; j < 8; j++) W1p[tid*8 + j] = tmp[j];
    } else if (tid < 8*8*64 + 4*4*64){
        int t = tid - 8*8*64;
        int kt = t >> 8, nt = (t >> 6) & 3, l = t & 63;
        int q = l >> 4, c = l & 15;
        ushort_t tmp[8];
        #pragma unroll
        for (int j = 0; j < 8; j++)
            tmp[j] = f2h(W2[(kt*32 + q*8 + j)*64 + nt*16 + c]);
        #pragma unroll
        for (int j = 0; j < 8; j++) W2p[t*8 + j] = tmp[j];
    }
}

// Pre-masked fp16 node table (2.5 MB, L2-resident) + fp16 global table.
__global__ void prep_tables(const float* __restrict__ node_attr,
                            const float* __restrict__ node_mask,
                            const float* __restrict__ global_attr,
                            ushort_t* __restrict__ node16,
                            ushort_t* __restrict__ glob16){
    int gid = blockIdx.x * 256 + threadIdx.x;
    if (gid < N_NODES * 8){                     // 8 elems per thread
        int r = gid >> 3, c8 = gid & 7;
        float m = node_mask[r];
        const float4* src = (const float4*)(node_attr + (size_t)r*64 + c8*8);
        float4 a = src[0], b = src[1];
        uint4 o;
        o.x = pk2h(a.x*m, a.y*m); o.y = pk2h(a.z*m, a.w*m);
        o.z = pk2h(b.x*m, b.y*m); o.w = pk2h(b.z*m, b.w*m);
        *(uint4*)(node16 + (size_t)r*64 + c8*8) = o;
    } else if (gid < N_NODES * 8 + 16 * 8){
        int t = gid - N_NODES * 8;
        int r = t >> 3, c8 = t & 7;
        const float4* src = (const float4*)(global_attr + (size_t)r*64 + c8*8);
        float4 a = src[0], b = src[1];
        uint4 o;
        o.x = pk2h(a.x, a.y); o.y = pk2h(a.z, a.w);
        o.z = pk2h(b.x, b.y); o.w = pk2h(b.z, b.w);
        *(uint4*)(glob16 + (size_t)r*64 + c8*8) = o;
    }
}

// K-split staging: X[128,256] is staged in two 128-col halves through one
// 33.8 KB buffer; GEMM1 accumulators persist across the split. LDS max is
// the Hs overlay (34.8 KB) -> 4 blocks/CU = 32 waves/CU (full occupancy).
// Per-block work, W-traffic, and numerics identical to the 127.8us version.
__global__ __launch_bounds__(512, 8)
void edge_mlp(const float* __restrict__ edge_attr,
              const float* __restrict__ edge_mask,
              const int*   __restrict__ edge_index,
              const int*   __restrict__ eg_index,
              const float* __restrict__ b1,
              const float* __restrict__ b2,
              const ushort_t* __restrict__ W1p,
              const ushort_t* __restrict__ W2p,
              const ushort_t* __restrict__ node16,
              const ushort_t* __restrict__ glob16,
              float*       __restrict__ out){
    __shared__ ushort_t S[M_BLK * HS_LD];    // 34,816 B
    ushort_t* Xs = S;                         // [M_BLK][XS2_LD] (16,896 elems)
    ushort_t* Hs = S;                         // [M_BLK][HS_LD] overlay

    const int tid = threadIdx.x;
    const int e0  = blockIdx.x * M_BLK;
    const int w   = tid >> 6, lane = tid & 63;
    const int q   = lane >> 4, cc = lane & 15;
    const int mt0 = (w >> 2) * 4;   // GEMM1: wave owns 4mt x 2nt
    const int nt0 = (w & 3) * 2;

    const short8* W1v = (const short8*)W1p;

    // ---- stage A: edge_attr (fp32->fp16) cols 0..63 | senders cols 64..127 ----
    {
        const float4* src = (const float4*)(edge_attr + (size_t)e0 * 64);
        #pragma unroll
        for (int k = 0; k < 4; k++){
            int idx = tid + k*512;            // 0..2047 ; 16 float4 per row
            int r = idx >> 4, c = idx & 15;
            float4 v = src[idx];
            uint2 o; o.x = pk2h(v.x, v.y); o.y = pk2h(v.z, v.w);
            *(uint2*)&Xs[r*XS2_LD + c*4] = o;
        }
        #pragma unroll
        for (int k = 0; k < 2; k++){
            int idx = tid + k*512;            // 0..1023 ; 8 x 16B per row
            int r = idx >> 3, c = idx & 7;
            int ei = edge_index[e0 + r];      // senders
            uint4 v = *(const uint4*)(node16 + (size_t)ei*64 + c*8);
            *(uint4*)&Xs[r*XS2_LD + 64 + c*8] = v;
        }
    }
    __syncthreads();

    // ---- GEMM1 part A: kt = 0..3 (K 0..127) ----
    floatx4 acc[4][2];
    #pragma unroll
    for (int i = 0; i < 4; i++)
        #pragma unroll
        for (int j = 0; j < 2; j++) acc[i][j] = (floatx4){0.f,0.f,0.f,0.f};

    #pragma unroll
    for (int kt = 0; kt < 4; kt++){
        short8 b[2];
        #pragma unroll
        for (int j = 0; j < 2; j++) b[j] = W1v[(kt*8 + nt0 + j)*64 + lane];
        #pragma unroll
        for (int i = 0; i < 4; i++){
            const short8 a = *(const short8*)&Xs[((mt0 + i)*16 + cc)*XS2_LD + kt*32 + q*8];
            #pragma unroll
            for (int j = 0; j < 2; j++)
                acc[i][j] = __builtin_amdgcn_mfma_f32_16x16x32_f16(a, b[j], acc[i][j], 0, 0, 0);
        }
    }
    __syncthreads();   // all reads of half A done before overwrite

    // ---- stage B: receivers cols 0..63 | globals cols 64..127 ----
    {
        #pragma unroll
        for (int k = 0; k < 2; k++){
            int idx = tid + k*512;
            int r = idx >> 3, c = idx & 7;
            int ei = edge_index[E_TOTAL + e0 + r];   // receivers
            uint4 v = *(const uint4*)(node16 + (size_t)ei*64 + c*8);
            *(uint4*)&Xs[r*XS2_LD + c*8] = v;
        }
        #pragma unroll
        for (int k = 0; k < 2; k++){
            int idx = tid + k*512;
            int r = idx >> 3, c = idx & 7;
            int g = eg_index[e0 + r];
            uint4 v = *(const uint4*)(glob16 + (size_t)g*64 + c*8);
            *(uint4*)&Xs[r*XS2_LD + 64 + c*8] = v;
        }
    }
    __syncthreads();

    // ---- GEMM1 part B: kt = 4..7 (K 128..255), buffer cols offset -128 ----
    #pragma unroll
    for (int kt = 4; kt < 8; kt++){
        short8 b[2];
        #pragma unroll
        for (int j = 0; j < 2; j++) b[j] = W1v[(kt*8 + nt0 + j)*64 + lane];
        #pragma unroll
        for (int i = 0; i < 4; i++){
            const short8 a = *(const short8*)&Xs[((mt0 + i)*16 + cc)*XS2_LD + (kt-4)*32 + q*8];
            #pragma unroll
            for (int j = 0; j < 2; j++)
                acc[i][j] = __builtin_amdgcn_mfma_f32_16x16x32_f16(a, b[j], acc[i][j], 0, 0, 0);
        }
    }
    __syncthreads();   // all reads done before Hs overlay

    // ---- epilogue 1: +b1, relu, fp16 -> Hs (row-major) ----
    #pragma unroll
    for (int j = 0; j < 2; j++){
        int col = (nt0 + j)*16 + cc;
        float bb = b1[col];
        #pragma unroll
        for (int i = 0; i < 4; i++){
            int rowb = (mt0 + i)*16 + q*4;
            #pragma unroll
            for (int r = 0; r < 4; r++){
                float v = acc[i][j][r] + bb;
                v = v > 0.f ? v : 0.f;
                Hs[(rowb + r)*HS_LD + col] = f2h(v);
            }
        }
    }
    __syncthreads();

    // ---- GEMM2: OUT[128,64] = H[128,128] @ W2 ; wave owns 2mt x 2nt ----
    const int mt20 = (w >> 1) * 2;  // 0,0,2,2,4,4,6,6
    const int nt20 = (w & 1) * 2;   // 0 or 2

    floatx4 acc2[2][2];
    #pragma unroll
    for (int i = 0; i < 2; i++)
        #pragma unroll
        for (int j = 0; j < 2; j++) acc2[i][j] = (floatx4){0.f,0.f,0.f,0.f};

    const short8* W2v = (const short8*)W2p;
    #pragma unroll
    for (int kt = 0; kt < 4; kt++){
        short8 b[2];
        #pragma unroll
        for (int j = 0; j < 2; j++) b[j] = W2v[(kt*4 + nt20 + j)*64 + lane];
        #pragma unroll
        for (int i = 0; i < 2; i++){
            const short8 a = *(const short8*)&Hs[((mt20 + i)*16 + cc)*HS_LD + kt*32 + q*8];
            #pragma unroll
            for (int j = 0; j < 2; j++)
                acc2[i][j] = __builtin_amdgcn_mfma_f32_16x16x32_f16(a, b[j], acc2[i][j], 0, 0, 0);
        }
    }

    // ---- epilogue 2: +b2, *edge_mask, store fp32 ----
    float bb2[2];
    #pragma unroll
    for (int j = 0; j < 2; j++) bb2[j] = b2[(nt20 + j)*16 + cc];
    #pragma unroll
    for (int i = 0; i < 2; i++){
        #pragma unroll
        for (int r = 0; r < 4; r++){
            int row = (mt20 + i)*16 + q*4 + r;
            float em = edge_mask[e0 + row];
            size_t base = (size_t)(e0 + row) * 64;
            #pragma unroll
            for (int j = 0; j < 2; j++)
                out[base + (nt20 + j)*16 + cc] = (acc2[i][j][r] + bb2[j]) * em;
        }
    }
}

// ---- Fallback: self-contained baseline (used only if workspace too small) ----
__global__ __launch_bounds__(512, 4)
void edge_mlp_fb(const float* __restrict__ node_attr,
                 const float* __restrict__ edge_attr,
                 const float* __restrict__ global_attr,
                 const float* __restrict__ node_mask,
                 const float* __restrict__ edge_mask,
                 const int*   __restrict__ edge_index,
                 const int*   __restrict__ eg_index,
                 const float* __restrict__ b1,
                 const float* __restrict__ b2,
                 const ushort_t* __restrict__ W1p,
                 const ushort_t* __restrict__ W2p,
                 float*       __restrict__ out){
    __shared__ ushort_t Xs[M_BLK * XS_LD];
    ushort_t* Hs = Xs;
    const int tid = threadIdx.x;
    const int e0  = blockIdx.x * M_BLK;
    {
        const float4* src = (const float4*)(edge_attr + (size_t)e0 * 64);
        #pragma unroll
        for (int k = 0; k < 4; k++){
            int idx = tid + k*512;
            int r = idx >> 4, c = idx & 15;
            float4 v = src[idx];
            uint2 o; o.x = pk2h(v.x, v.y); o.y = pk2h(v.z, v.w);
            *(uint2*)&Xs[r*XS_LD + c*4] = o;
        }
    }
    {
        #pragma unroll
        for (int k = 0; k < 4; k++){
            int idx = tid + k*512; int r = idx >> 4, c = idx & 15;
            int g = eg_index[e0 + r];
            const float4* src = (const float4*)(global_attr + (size_t)g * 64);
            float4 v = src[c];
            uint2 o; o.x = pk2h(v.x, v.y); o.y = pk2h(v.z, v.w);
            *(uint2*)&Xs[r*XS_LD + 192 + c*4] = o;
        }
    }
    {
        int r = tid >> 2, seg = (tid >> 1) & 1, half = tid & 1;
        int idx = edge_index[seg*E_TOTAL + e0 + r];
        float m = node_mask[idx];
        const float4* src = (const float4*)(node_attr + (size_t)idx * 64) + half*8;
        ushort_t* dst = &Xs[r*XS_LD + 64 + seg*64 + half*32];
        #pragma unroll
        for (int c2 = 0; c2 < 8; c2++){
            float4 v = src[c2];
            uint2 o; o.x = pk2h(v.x*m, v.y*m); o.y = pk2h(v.z*m, v.w*m);
            *(uint2*)(dst + c2*4) = o;
        }
    }
    __syncthreads();

    const int w  = tid >> 6, lane = tid & 63;
    const int q  = lane >> 4, cc = lane & 15;
    const int mt0 = (w >> 2) * 4;
    const int nt0 = (w & 3) * 2;

    floatx4 acc[4][2];
    #pragma unroll
    for (int i = 0; i < 4; i++)
        #pragma unroll
        for (int j = 0; j < 2; j++) acc[i][j] = (floatx4){0.f,0.f,0.f,0.f};

    const short8* W1v = (const short8*)W1p;
    #pragma unroll
    for (int kt = 0; kt < 8; kt++){
        short8 b[2];
        #pragma unroll
        for (int j = 0; j < 2; j++) b[j] = W1v[(kt*8 + nt0 + j)*64 + lane];
        #pragma unroll
        for (int i = 0; i < 4; i++){
            const short8 a = *(const short8*)&Xs[((mt0 + i)*16 + cc)*XS_LD + kt*32 + q*8];
            #pragma unroll
            for (int j = 0; j < 2; j++)
                acc[i][j] = __builtin_amdgcn_mfma_f32_16x16x32_f16(a, b[j], acc[i][j], 0, 0, 0);
        }
    }
    __syncthreads();

    #pragma unroll
    for (int j = 0; j < 2; j++){
        int col = (nt0 + j)*16 + cc;
        float bb = b1[col];
        #pragma unroll
        for (int i = 0; i < 4; i++){
            int rowb = (mt0 + i)*16 + q*4;
            #pragma unroll
            for (int r = 0; r < 4; r++){
                float v = acc[i][j][r] + bb;
                v = v > 0.f ? v : 0.f;
                Hs[(rowb + r)*HS_LD + col] = f2h(v);
            }
        }
    }
    __syncthreads();

    const int mt20 = (w >> 1) * 2;
    const int nt20 = (w & 1) * 2;

    floatx4 acc2[2][2];
    #pragma unroll
    for (int i = 0; i < 2; i++)
        #pragma unroll
        for (int j = 0; j < 2; j++) acc2[i][j] = (floatx4){0.f,0.f,0.f,0.f};

    const short8* W2v = (const short8*)W2p;
    #pragma unroll
    for (int kt = 0; kt < 4; kt++){
        short8 b[2];
        #pragma unroll
        for (int j = 0; j < 2; j++) b[j] = W2v[(kt*4 + nt20 + j)*64 + lane];
        #pragma unroll
        for (int i = 0; i < 2; i++){
            const short8 a = *(const short8*)&Hs[((mt20 + i)*16 + cc)*HS_LD + kt*32 + q*8];
            #pragma unroll
            for (int j = 0; j < 2; j++)
                acc2[i][j] = __builtin_amdgcn_mfma_f32_16x16x32_f16(a, b[j], acc2[i][j], 0, 0, 0);
        }
    }

    float bb2[2];
    #pragma unroll
    for (int j = 0; j < 2; j++) bb2[j] = b2[(nt20 + j)*16 + cc];
    #pragma unroll
    for (int i = 0; i < 2; i++){
        #pragma unroll
        for (int r = 0; r < 4; r++){
            int row = (mt20 + i)*16 + q*4 + r;
            float em = edge_mask[e0 + row];
            size_t base = (size_t)(e0 + row) * 64;
            #pragma unroll
            for (int j = 0; j < 2; j++)
                out[base + (nt20 + j)*16 + cc] = (acc2[i][j][r] + bb2[j]) * em;
        }
    }
}

extern "C" void kernel_launch(void* const* d_in, const int* in_sizes, int n_in,
                              void* d_out, int out_size, void* d_ws, size_t ws_size,
                              hipStream_t stream){
    const float* node_attr   = (const float*)d_in[0];
    const float* edge_attr   = (const float*)d_in[1];
    const float* global_attr = (const float*)d_in[2];
    const float* node_mask   = (const float*)d_in[3];
    const float* edge_mask   = (const float*)d_in[4];
    const int*   edge_index  = (const int*)d_in[5];
    const int*   eg_index    = (const int*)d_in[6];
    const float* W1          = (const float*)d_in[7];
    const float* b1          = (const float*)d_in[8];
    const float* W2          = (const float*)d_in[9];
    const float* b2          = (const float*)d_in[10];

    ushort_t* W1p = (ushort_t*)d_ws;            // 32768 elems (64 KB)
    ushort_t* W2p = W1p + 8*8*64*8;             //  8192 elems (16 KB)
    ushort_t* node16 = W2p + 4*4*64*8;          // 20000*64 elems (2.5 MB)
    ushort_t* glob16 = node16 + (size_t)N_NODES*64; // 16*64 elems (2 KB)

    size_t need = (size_t)(8*8*64*8 + 4*4*64*8 + N_NODES*64 + 16*64) * sizeof(ushort_t);

    repack_w<<<20, 256, 0, stream>>>(W1, W2, W1p, W2p);
    if (ws_size >= need){
        prep_tables<<<(N_NODES*8 + 16*8 + 255)/256, 256, 0, stream>>>(
            node_attr, node_mask, global_attr, node16, glob16);
        edge_mlp<<<N_TILES, 512, 0, stream>>>(
            edge_attr, edge_mask, edge_index, eg_index,
            b1, b2, W1p, W2p, node16, glob16, (float*)d_out);
    } else {
        edge_mlp_fb<<<N_TILES, 512, 0, stream>>>(
            node_attr, edge_attr, global_attr, node_mask, edge_mask,
            edge_index, eg_index, b1, b2, W1p, W2p, (float*)d_out);
    }
}